// Round 4
// baseline (150.131 us; speedup 1.0000x reference)
//
#include <hip/hip_runtime.h>
#include <math.h>

#define NTYPE   4
#define NWAVE   8
#define NORBIT  128
#define NEIGH   64
#define NB      32
#define NATOM   256
#define NPP     (NATOM * NEIGH)   /* 16384 pairs per batch */
#define NPAIR   (NB * NPP)        /* 524288 */
#define TOTATOM (NB * NATOM)      /* 8192  */
#define NPARA   13                /* 1 + 3 + 9 */
#define CAP     128               /* slots per atom; P(overflow) ~1e-15 */

#define SC_CHUNK 2048             /* pairs per scatter block */
#define SC_BPB   8                /* scatter blocks per batch */
#define SC_NBLK  (NB * SC_BPB)    /* 256 */

__device__ __forceinline__ float fast_tanh(float x) {
    float ax = fabsf(x);
    float e  = __expf(-2.0f * ax);
    float r  = (1.0f - e) / (1.0f + e);
    return copysignf(r, x);
}

// ---- scatter via global atomic-append; geometry (d, fc) hoisted here -------
__global__ __launch_bounds__(256) void k_scatter(const int* __restrict__ atom_index,
                                                 const float* __restrict__ cart,
                                                 const float* __restrict__ shifts,
                                                 const int* __restrict__ species,
                                                 int* __restrict__ cnt,
                                                 float4* __restrict__ rec,
                                                 float2* __restrict__ df) {
    const int bl = blockIdx.x, t = threadIdx.x;
    const int b = bl >> 3, c = bl & 7;
    __shared__ float cx[NATOM], cy[NATOM], cz[NATOM];
    __shared__ int spl[NATOM];
    const int ag = b * NATOM + t;
    cx[t] = cart[ag * 3 + 0];
    cy[t] = cart[ag * 3 + 1];
    cz[t] = cart[ag * 3 + 2];
    spl[t] = species[ag];
    __syncthreads();
    const int base = b * NPP + c * SC_CHUNK;
#pragma unroll
    for (int k = 0; k < SC_CHUNK / 256; k++) {
        int p = base + t + k * 256;
        int i = atom_index[p];
        int j = atom_index[NPAIR + p];
        float dx = cx[i] - cx[j] + shifts[p * 3 + 0];
        float dy = cy[i] - cy[j] + shifts[p * 3 + 1];
        float dz = cz[i] - cz[j] + shifts[p * 3 + 2];
        float d2 = dx * dx + dy * dy + dz * dz;
        float d  = sqrtf(d2);
        float cc = __cosf(d * 0.62831853071795864769f); // pi / CUTOFF
        float fc = 0.5f * cc + 0.5f;
        fc = fc * fc;
        int ig = b * NATOM + i;
        int jg = b * NATOM + j;
        int pos = atomicAdd(&cnt[ig], 1);
        if (pos < CAP) {
            rec[(size_t)ig * CAP + pos] =
                make_float4(dx, dy, dz, __int_as_float(jg | (spl[j] << 16)));
            df[(size_t)ig * CAP + pos] = make_float2(d, fc);
        }
    }
}

// ---- fused obtain() + coeff update -----------------------------------------
// MODE 0: coeff_out = cin + tanh(density @ W + E[species]);  MODE 1: write density.
// INL: round 0 — orbital coeff is params[species[j]][w], held in registers; no gather.
template <int MODE, bool INL>
__global__ __launch_bounds__(256) void k_density(const float4* __restrict__ rec,
                                                 const float2* __restrict__ df,
                                                 const int* __restrict__ cnt,
                                                 const float* __restrict__ coeff_in,
                                                 const float* __restrict__ rs,
                                                 const float* __restrict__ inta,
                                                 const float* __restrict__ params,
                                                 const float* __restrict__ hyper,
                                                 const float* __restrict__ W,
                                                 const float* __restrict__ E,
                                                 const int* __restrict__ species,
                                                 float* __restrict__ coeff_out,
                                                 float* __restrict__ density_out) {
    const int wv = threadIdx.x >> 6;
    const int lane = threadIdx.x & 63;
    const int a = blockIdx.x * 4 + wv;
    const int pl = lane >> 3;       // pair sub-lane 0..7
    const int w  = lane & 7;        // wave channel 0..7

    // register-resident per-species tables for this lane's w
    float rs0 = rs[w],   rs1 = rs[8 + w],   rs2 = rs[16 + w],   rs3 = rs[24 + w];
    float in0 = inta[w], in1 = inta[8 + w], in2 = inta[16 + w], in3 = inta[24 + w];
    float pm0 = 0.f, pm1 = 0.f, pm2 = 0.f, pm3 = 0.f;
    if (INL) {
        pm0 = params[w];      pm1 = params[8 + w];
        pm2 = params[16 + w]; pm3 = params[24 + w];
    }

    // batch-local coeff slice staged in LDS (gather rounds only):
    // block's 4 atoms all lie in one batch (64 blocks per batch).
    __shared__ float cshared[NATOM * NWAVE];   // 8 KiB
    if (!INL) {
        const int cbase = (blockIdx.x >> 6) * (NATOM * NWAVE);
        const int t = threadIdx.x;
#pragma unroll
        for (int k = 0; k < (NATOM * NWAVE) / 256; k++)
            cshared[t + k * 256] = coeff_in[cbase + t + k * 256];
        __syncthreads();
    }

    const int n = cnt[a];
    const float4* rbase = rec + (size_t)a * CAP;
    const float2* fbase = df  + (size_t)a * CAP;

    float S[NPARA];
#pragma unroll
    for (int k = 0; k < NPARA; k++) S[k] = 0.0f;

    int idx = pl;
    float4 r = make_float4(0.f, 0.f, 0.f, 0.f);
    float2 f = make_float2(0.f, 0.f);
    if (idx < n) { r = rbase[idx]; f = fbase[idx]; }
    for (; idx < n; idx += 8) {
        int nidx = idx + 8;
        float4 rn = r;
        float2 fn = f;
        if (nidx < n) { rn = rbase[nidx]; fn = fbase[nidx]; }   // prefetch
        int jp = __float_as_int(r.w);
        int sp = jp >> 16;
        float cj;
        if (INL) {
            cj = (sp == 0) ? pm0 : (sp == 1) ? pm1 : (sp == 2) ? pm2 : pm3;
        } else {
            cj = cshared[(jp & 0xFF) * NWAVE + w];   // LDS gather, conflict-free
        }
        float rw = (sp == 0) ? rs0 : (sp == 1) ? rs1 : (sp == 2) ? rs2 : rs3;
        float iw = (sp == 0) ? in0 : (sp == 1) ? in1 : (sp == 2) ? in2 : in3;
        float dr  = f.x - rw;
        float rad = __expf(iw * dr * dr);
        float q = f.y * rad * cj;
        S[0] += q;
        float qx = q * r.x, qy = q * r.y, qz = q * r.z;
        S[1] += qx; S[2] += qy; S[3] += qz;
        S[4]  += qx * r.x; S[5]  += qx * r.y; S[6]  += qx * r.z;
        S[7]  += qy * r.x; S[8]  += qy * r.y; S[9]  += qy * r.z;
        S[10] += qz * r.x; S[11] += qz * r.y; S[12] += qz * r.z;
        r = rn;
        f = fn;
    }

    // reduce over the 8 pair sub-lanes (lanes sharing w differ in bits 3..5)
#pragma unroll
    for (int k = 0; k < NPARA; k++) {
        S[k] += __shfl_xor(S[k], 8, 64);
        S[k] += __shfl_xor(S[k], 16, 64);
        S[k] += __shfl_xor(S[k], 32, 64);
    }

    // transposed stash: lds_S[wv][w*16 + para]  (stride 16 -> b128-aligned rows)
    __shared__ float lds_S[4][NWAVE * 16];
    if (pl == 0) {
#pragma unroll
        for (int k = 0; k < NPARA; k++) lds_S[wv][w * 16 + k] = S[k];
    }
    __syncthreads();

    // projection with hw-accumulators: hyper read once per (w,ip) -> 48 loads
    const int o0 = lane, o1 = lane + 64;
    float hw0[NPARA], hw1[NPARA];
#pragma unroll
    for (int k = 0; k < NPARA; k++) { hw0[k] = 0.0f; hw1[k] = 0.0f; }
#pragma unroll
    for (int w2 = 0; w2 < NWAVE; w2++) {
        const float* Sw = &lds_S[wv][w2 * 16];
        float4 s0 = *(const float4*)(Sw);        // S[0..3]  (broadcast ds_read_b128)
        float4 s1 = *(const float4*)(Sw + 4);    // S[4..7]
        float4 s2 = *(const float4*)(Sw + 8);    // S[8..11]
        float  sc = Sw[12];                      // S[12]
        float h00 = hyper[w2 * NORBIT + o0];
        float h01 = hyper[w2 * NORBIT + o1];
        float h10 = hyper[(NWAVE + w2) * NORBIT + o0];
        float h11 = hyper[(NWAVE + w2) * NORBIT + o1];
        float h20 = hyper[(2 * NWAVE + w2) * NORBIT + o0];
        float h21 = hyper[(2 * NWAVE + w2) * NORBIT + o1];
        hw0[0]  += s0.x * h00; hw1[0]  += s0.x * h01;
        hw0[1]  += s0.y * h10; hw1[1]  += s0.y * h11;
        hw0[2]  += s0.z * h10; hw1[2]  += s0.z * h11;
        hw0[3]  += s0.w * h10; hw1[3]  += s0.w * h11;
        hw0[4]  += s1.x * h20; hw1[4]  += s1.x * h21;
        hw0[5]  += s1.y * h20; hw1[5]  += s1.y * h21;
        hw0[6]  += s1.z * h20; hw1[6]  += s1.z * h21;
        hw0[7]  += s1.w * h20; hw1[7]  += s1.w * h21;
        hw0[8]  += s2.x * h20; hw1[8]  += s2.x * h21;
        hw0[9]  += s2.y * h20; hw1[9]  += s2.y * h21;
        hw0[10] += s2.z * h20; hw1[10] += s2.z * h21;
        hw0[11] += s2.w * h20; hw1[11] += s2.w * h21;
        hw0[12] += sc   * h20; hw1[12] += sc   * h21;
    }
    float acc0 = 0.0f, acc1 = 0.0f;
#pragma unroll
    for (int k = 0; k < NPARA; k++) {
        acc0 += hw0[k] * hw0[k];
        acc1 += hw1[k] * hw1[k];
    }

    if (MODE == 1) {
        density_out[a * NORBIT + o0] = acc0;
        density_out[a * NORBIT + o1] = acc1;
        return;
    }

    // fused coeff update: part[w] = sum_o density[o] * W[o][w]
    float part[NWAVE];
#pragma unroll
    for (int w2 = 0; w2 < NWAVE; w2++)
        part[w2] = acc0 * W[o0 * NWAVE + w2] + acc1 * W[o1 * NWAVE + w2];
#pragma unroll
    for (int mask = 1; mask < 64; mask <<= 1) {
#pragma unroll
        for (int w2 = 0; w2 < NWAVE; w2++)
            part[w2] += __shfl_xor(part[w2], mask, 64);
    }
    if (lane < NWAVE) {
        int sp = species[a];
        float cin_v;
        if (INL) cin_v = params[sp * NWAVE + lane];
        else     cin_v = cshared[(a & (NATOM - 1)) * NWAVE + lane];
        coeff_out[a * NWAVE + lane] =
            cin_v + fast_tanh(part[lane] + E[sp * NWAVE + lane]);
    }
}

extern "C" void kernel_launch(void* const* d_in, const int* in_sizes, int n_in,
                              void* d_out, int out_size, void* d_ws, size_t ws_size,
                              hipStream_t stream) {
    const float* cart    = (const float*)d_in[0];
    const float* shifts  = (const float*)d_in[1];
    const float* rs      = (const float*)d_in[2];
    const float* inta    = (const float*)d_in[3];
    const float* params  = (const float*)d_in[4];
    const float* hyper   = (const float*)d_in[5];
    const float* w0      = (const float*)d_in[6];
    const float* e0      = (const float*)d_in[7];
    const float* w1      = (const float*)d_in[8];
    const float* e1      = (const float*)d_in[9];
    // d_in[10] = numatoms (unused, always NATOM)
    const int* species    = (const int*)d_in[11];
    const int* atom_index = (const int*)d_in[12];
    float* out = (float*)d_out;

    char* ws = (char*)d_ws;
    float4* rec   = (float4*)ws; ws += (size_t)TOTATOM * CAP * 16;     // 16 MiB
    float2* df    = (float2*)ws; ws += (size_t)TOTATOM * CAP * 8;      // 8 MiB
    float* coeffA = (float*)ws;  ws += (size_t)TOTATOM * NWAVE * 4;    // 256 KiB
    float* coeffB = (float*)ws;  ws += (size_t)TOTATOM * NWAVE * 4;    // 256 KiB
    int* cnt      = (int*)ws;    ws += (size_t)TOTATOM * 4;            // 32 KiB

    hipMemsetAsync(cnt, 0, (size_t)TOTATOM * 4, stream);
    k_scatter<<<SC_NBLK, 256, 0, stream>>>(atom_index, cart, shifts, species,
                                           cnt, rec, df);

    k_density<0, true ><<<TOTATOM / 4, 256, 0, stream>>>(rec, df, cnt, nullptr, rs, inta,
                                                         params, hyper, w0, e0, species,
                                                         coeffB, out);
    k_density<0, false><<<TOTATOM / 4, 256, 0, stream>>>(rec, df, cnt, coeffB, rs, inta,
                                                         params, hyper, w1, e1, species,
                                                         coeffA, out);
    k_density<1, false><<<TOTATOM / 4, 256, 0, stream>>>(rec, df, cnt, coeffA, rs, inta,
                                                         params, hyper, w1, e1, species,
                                                         nullptr, out);
}

// Round 5
// 149.335 us; speedup vs baseline: 1.0053x; 1.0053x over previous
//
#include <hip/hip_runtime.h>
#include <math.h>

#define NTYPE   4
#define NWAVE   8
#define NORBIT  128
#define NEIGH   64
#define NB      32
#define NATOM   256
#define NPP     (NATOM * NEIGH)   /* 16384 pairs per batch */
#define NPAIR   (NB * NPP)        /* 524288 */
#define TOTATOM (NB * NATOM)      /* 8192  */
#define NPARA   13                /* 1 + 3 + 9 */
#define CAP     128               /* slots per atom; P(overflow) ~1e-15 */

#define SC_CHUNK 2048             /* pairs per scatter block */
#define SC_BPB   8                /* scatter blocks per batch */
#define SC_NBLK  (NB * SC_BPB)    /* 256 */

__device__ __forceinline__ float fast_tanh(float x) {
    float ax = fabsf(x);
    float e  = __expf(-2.0f * ax);
    float r  = (1.0f - e) / (1.0f + e);
    return copysignf(r, x);
}

// ---- scatter via global atomic-append (replaces hist+offsets+scatter) ------
__global__ __launch_bounds__(256) void k_scatter(const int* __restrict__ atom_index,
                                                 const float* __restrict__ cart,
                                                 const float* __restrict__ shifts,
                                                 const int* __restrict__ species,
                                                 int* __restrict__ cnt,
                                                 float4* __restrict__ rec) {
    const int bl = blockIdx.x, t = threadIdx.x;
    const int b = bl >> 3, c = bl & 7;
    __shared__ float cx[NATOM], cy[NATOM], cz[NATOM];
    __shared__ int spl[NATOM];
    const int ag = b * NATOM + t;
    cx[t] = cart[ag * 3 + 0];
    cy[t] = cart[ag * 3 + 1];
    cz[t] = cart[ag * 3 + 2];
    spl[t] = species[ag];
    __syncthreads();
    const int base = b * NPP + c * SC_CHUNK;
#pragma unroll
    for (int k = 0; k < SC_CHUNK / 256; k++) {
        int p = base + t + k * 256;
        int i = atom_index[p];
        int j = atom_index[NPAIR + p];
        float dx = cx[i] - cx[j] + shifts[p * 3 + 0];
        float dy = cy[i] - cy[j] + shifts[p * 3 + 1];
        float dz = cz[i] - cz[j] + shifts[p * 3 + 2];
        int ig = b * NATOM + i;
        int jg = b * NATOM + j;
        int pos = atomicAdd(&cnt[ig], 1);
        if (pos < CAP)
            rec[(size_t)ig * CAP + pos] =
                make_float4(dx, dy, dz, __int_as_float(jg | (spl[j] << 16)));
    }
}

// ---- fused obtain() + coeff update -----------------------------------------
// MODE 0: coeff_out = cin + tanh(density @ W + E[species]);  MODE 1: write density.
// INL: round 0 — orbital coeff is params[species[j]][w], held in registers; no gather.
template <int MODE, bool INL>
__global__ __launch_bounds__(256) void k_density(const float4* __restrict__ rec,
                                                 const int* __restrict__ cnt,
                                                 const float* __restrict__ coeff_in,
                                                 const float* __restrict__ rs,
                                                 const float* __restrict__ inta,
                                                 const float* __restrict__ params,
                                                 const float* __restrict__ hyper,
                                                 const float* __restrict__ W,
                                                 const float* __restrict__ E,
                                                 const int* __restrict__ species,
                                                 float* __restrict__ coeff_out,
                                                 float* __restrict__ density_out) {
    const int wv = threadIdx.x >> 6;
    const int lane = threadIdx.x & 63;
    const int a = blockIdx.x * 4 + wv;
    const int pl = lane >> 3;       // pair sub-lane 0..7
    const int w  = lane & 7;        // wave channel 0..7

    // register-resident per-species tables for this lane's w
    float rs0 = rs[w],   rs1 = rs[8 + w],   rs2 = rs[16 + w],   rs3 = rs[24 + w];
    float in0 = inta[w], in1 = inta[8 + w], in2 = inta[16 + w], in3 = inta[24 + w];
    float pm0 = 0.f, pm1 = 0.f, pm2 = 0.f, pm3 = 0.f;
    if (INL) {
        pm0 = params[w];      pm1 = params[8 + w];
        pm2 = params[16 + w]; pm3 = params[24 + w];
    }

    const int n = cnt[a];
    const float4* rbase = rec + (size_t)a * CAP;

    float S[NPARA];
#pragma unroll
    for (int k = 0; k < NPARA; k++) S[k] = 0.0f;

    int idx = pl;
    float4 r = make_float4(0.f, 0.f, 0.f, 0.f);
    if (idx < n) r = rbase[idx];
    for (; idx < n; idx += 8) {
        int nidx = idx + 8;
        float4 rn = r;
        if (nidx < n) rn = rbase[nidx];           // prefetch next record
        int jp = __float_as_int(r.w);
        int sp = jp >> 16;
        float cj;
        if (INL) {
            cj = (sp == 0) ? pm0 : (sp == 1) ? pm1 : (sp == 2) ? pm2 : pm3;
        } else {
            int j = jp & 0xFFFF;
            cj = coeff_in[j * NWAVE + w];         // gather (L1/L2)
        }
        float d2 = r.x * r.x + r.y * r.y + r.z * r.z;
        float d  = sqrtf(d2);
        float c  = __cosf(d * 0.62831853071795864769f); // pi / CUTOFF
        float fc = 0.5f * c + 0.5f;
        fc = fc * fc;
        float rw = (sp == 0) ? rs0 : (sp == 1) ? rs1 : (sp == 2) ? rs2 : rs3;
        float iw = (sp == 0) ? in0 : (sp == 1) ? in1 : (sp == 2) ? in2 : in3;
        float dr  = d - rw;
        float rad = __expf(iw * dr * dr);
        float q = fc * rad * cj;
        S[0] += q;
        float qx = q * r.x, qy = q * r.y, qz = q * r.z;
        S[1] += qx; S[2] += qy; S[3] += qz;
        S[4]  += qx * r.x; S[5]  += qx * r.y; S[6]  += qx * r.z;
        S[7]  += qy * r.x; S[8]  += qy * r.y; S[9]  += qy * r.z;
        S[10] += qz * r.x; S[11] += qz * r.y; S[12] += qz * r.z;
        r = rn;
    }

    // reduce over the 8 pair sub-lanes (lanes sharing w differ in bits 3..5)
#pragma unroll
    for (int k = 0; k < NPARA; k++) {
        S[k] += __shfl_xor(S[k], 8, 64);
        S[k] += __shfl_xor(S[k], 16, 64);
        S[k] += __shfl_xor(S[k], 32, 64);
    }

    // transposed stash: lds_S[wv][w*16 + para]  (stride 16 -> b128-aligned rows)
    __shared__ float lds_S[4][NWAVE * 16];
    if (pl == 0) {
#pragma unroll
        for (int k = 0; k < NPARA; k++) lds_S[wv][w * 16 + k] = S[k];
    }
    __syncthreads();

    // projection with hw-accumulators: hyper read once per (w,ip) -> 48 loads
    const int o0 = lane, o1 = lane + 64;
    float hw0[NPARA], hw1[NPARA];
#pragma unroll
    for (int k = 0; k < NPARA; k++) { hw0[k] = 0.0f; hw1[k] = 0.0f; }
#pragma unroll
    for (int w2 = 0; w2 < NWAVE; w2++) {
        const float* Sw = &lds_S[wv][w2 * 16];
        float4 s0 = *(const float4*)(Sw);        // S[0..3]  (broadcast ds_read_b128)
        float4 s1 = *(const float4*)(Sw + 4);    // S[4..7]
        float4 s2 = *(const float4*)(Sw + 8);    // S[8..11]
        float  sc = Sw[12];                      // S[12]
        float h00 = hyper[w2 * NORBIT + o0];
        float h01 = hyper[w2 * NORBIT + o1];
        float h10 = hyper[(NWAVE + w2) * NORBIT + o0];
        float h11 = hyper[(NWAVE + w2) * NORBIT + o1];
        float h20 = hyper[(2 * NWAVE + w2) * NORBIT + o0];
        float h21 = hyper[(2 * NWAVE + w2) * NORBIT + o1];
        hw0[0]  += s0.x * h00; hw1[0]  += s0.x * h01;
        hw0[1]  += s0.y * h10; hw1[1]  += s0.y * h11;
        hw0[2]  += s0.z * h10; hw1[2]  += s0.z * h11;
        hw0[3]  += s0.w * h10; hw1[3]  += s0.w * h11;
        hw0[4]  += s1.x * h20; hw1[4]  += s1.x * h21;
        hw0[5]  += s1.y * h20; hw1[5]  += s1.y * h21;
        hw0[6]  += s1.z * h20; hw1[6]  += s1.z * h21;
        hw0[7]  += s1.w * h20; hw1[7]  += s1.w * h21;
        hw0[8]  += s2.x * h20; hw1[8]  += s2.x * h21;
        hw0[9]  += s2.y * h20; hw1[9]  += s2.y * h21;
        hw0[10] += s2.z * h20; hw1[10] += s2.z * h21;
        hw0[11] += s2.w * h20; hw1[11] += s2.w * h21;
        hw0[12] += sc   * h20; hw1[12] += sc   * h21;
    }
    float acc0 = 0.0f, acc1 = 0.0f;
#pragma unroll
    for (int k = 0; k < NPARA; k++) {
        acc0 += hw0[k] * hw0[k];
        acc1 += hw1[k] * hw1[k];
    }

    if (MODE == 1) {
        density_out[a * NORBIT + o0] = acc0;
        density_out[a * NORBIT + o1] = acc1;
        return;
    }

    // fused coeff update: part[w] = sum_o density[o] * W[o][w]
    float part[NWAVE];
#pragma unroll
    for (int w2 = 0; w2 < NWAVE; w2++)
        part[w2] = acc0 * W[o0 * NWAVE + w2] + acc1 * W[o1 * NWAVE + w2];
#pragma unroll
    for (int mask = 1; mask < 64; mask <<= 1) {
#pragma unroll
        for (int w2 = 0; w2 < NWAVE; w2++)
            part[w2] += __shfl_xor(part[w2], mask, 64);
    }
    if (lane < NWAVE) {
        int sp = species[a];
        float cin_v;
        if (INL) cin_v = params[sp * NWAVE + lane];
        else     cin_v = coeff_in[a * NWAVE + lane];
        coeff_out[a * NWAVE + lane] =
            cin_v + fast_tanh(part[lane] + E[sp * NWAVE + lane]);
    }
}

extern "C" void kernel_launch(void* const* d_in, const int* in_sizes, int n_in,
                              void* d_out, int out_size, void* d_ws, size_t ws_size,
                              hipStream_t stream) {
    const float* cart    = (const float*)d_in[0];
    const float* shifts  = (const float*)d_in[1];
    const float* rs      = (const float*)d_in[2];
    const float* inta    = (const float*)d_in[3];
    const float* params  = (const float*)d_in[4];
    const float* hyper   = (const float*)d_in[5];
    const float* w0      = (const float*)d_in[6];
    const float* e0      = (const float*)d_in[7];
    const float* w1      = (const float*)d_in[8];
    const float* e1      = (const float*)d_in[9];
    // d_in[10] = numatoms (unused, always NATOM)
    const int* species    = (const int*)d_in[11];
    const int* atom_index = (const int*)d_in[12];
    float* out = (float*)d_out;

    char* ws = (char*)d_ws;
    float4* rec   = (float4*)ws; ws += (size_t)TOTATOM * CAP * 16;     // 16 MiB
    float* coeffA = (float*)ws;  ws += (size_t)TOTATOM * NWAVE * 4;    // 256 KiB
    float* coeffB = (float*)ws;  ws += (size_t)TOTATOM * NWAVE * 4;    // 256 KiB
    int* cnt      = (int*)ws;    ws += (size_t)TOTATOM * 4;            // 32 KiB

    hipMemsetAsync(cnt, 0, (size_t)TOTATOM * 4, stream);
    k_scatter<<<SC_NBLK, 256, 0, stream>>>(atom_index, cart, shifts, species, cnt, rec);

    k_density<0, true ><<<TOTATOM / 4, 256, 0, stream>>>(rec, cnt, nullptr, rs, inta,
                                                         params, hyper, w0, e0, species,
                                                         coeffB, out);
    k_density<0, false><<<TOTATOM / 4, 256, 0, stream>>>(rec, cnt, coeffB, rs, inta,
                                                         params, hyper, w1, e1, species,
                                                         coeffA, out);
    k_density<1, false><<<TOTATOM / 4, 256, 0, stream>>>(rec, cnt, coeffA, rs, inta,
                                                         params, hyper, w1, e1, species,
                                                         nullptr, out);
}